// Round 1
// baseline (262.488 us; speedup 1.0000x reference)
//
#include <hip/hip_runtime.h>

#define ITERS 20
#define EPS 1e-9f

// One wave (64 lanes) per 64x64 matrix. Lane (bi,bj) owns the 8x8 sub-block
// rows [8bi,8bi+8), cols [8bj,8bj+8), plus replicated scale vectors
// uu[r]=u[8bi+r], vv[c]=v[8bj+c]. Sinkhorn iterate is M = E .* (u v^T),
// so only u,v are updated; matrix E=exp(x) stays in registers.
__global__ __launch_bounds__(256, 3) void sinkhorn_kernel(
        const float* __restrict__ x, float* __restrict__ out, int nmat) {
    const int lane = threadIdx.x & 63;
    const int wave = threadIdx.x >> 6;
    const int mat  = blockIdx.x * 4 + wave;
    if (mat >= nmat) return;
    const int bi = lane >> 3;   // block-row 0..7
    const int bj = lane & 7;    // block-col 0..7

    const float4* __restrict__ xin = (const float4*)(x + (size_t)mat * 4096);

    // Load 8x8 block as 2 float4 per row, apply exp.
    float b[8][8];
    #pragma unroll
    for (int r = 0; r < 8; ++r) {
        // float4 index of (row 8bi+r, col 8bj): (8bi+r)*16 + 2bj
        float4 lo = xin[(8 * bi + r) * 16 + 2 * bj + 0];
        float4 hi = xin[(8 * bi + r) * 16 + 2 * bj + 1];
        b[r][0] = __expf(lo.x); b[r][1] = __expf(lo.y);
        b[r][2] = __expf(lo.z); b[r][3] = __expf(lo.w);
        b[r][4] = __expf(hi.x); b[r][5] = __expf(hi.y);
        b[r][6] = __expf(hi.z); b[r][7] = __expf(hi.w);
    }

    float uu[8], vv[8];
    #pragma unroll
    for (int i = 0; i < 8; ++i) { uu[i] = 1.0f; vv[i] = 1.0f; }

    for (int it = 0; it < ITERS; ++it) {
        // ---- row normalization: R_i = u_i * sum_j E[i,j] v_j ----
        float p[8];
        #pragma unroll
        for (int r = 0; r < 8; ++r) {
            float s = 0.0f;
            #pragma unroll
            for (int c = 0; c < 8; ++c) s = fmaf(b[r][c], vv[c], s);
            p[r] = s;
        }
        // butterfly all-reduce across the 8 lanes sharing bi (masks 1,2,4)
        #pragma unroll
        for (int m = 1; m <= 4; m <<= 1) {
            #pragma unroll
            for (int r = 0; r < 8; ++r) p[r] += __shfl_xor(p[r], m, 64);
        }
        #pragma unroll
        for (int r = 0; r < 8; ++r) {
            float S = fmaf(uu[r], p[r], EPS);      // rowsum + eps
            uu[r] *= __builtin_amdgcn_rcpf(S);
        }

        // ---- col normalization: C_j = v_j * sum_i E[i,j] u_i ----
        float q[8];
        #pragma unroll
        for (int c = 0; c < 8; ++c) {
            float s = 0.0f;
            #pragma unroll
            for (int r = 0; r < 8; ++r) s = fmaf(b[r][c], uu[r], s);
            q[c] = s;
        }
        // butterfly all-reduce across the 8 lanes sharing bj (masks 8,16,32)
        #pragma unroll
        for (int m = 8; m <= 32; m <<= 1) {
            #pragma unroll
            for (int c = 0; c < 8; ++c) q[c] += __shfl_xor(q[c], m, 64);
        }
        #pragma unroll
        for (int c = 0; c < 8; ++c) {
            float T = fmaf(vv[c], q[c], EPS);      // colsum + eps
            vv[c] *= __builtin_amdgcn_rcpf(T);
        }
    }

    // ---- epilogue: out = E .* (u v^T) ----
    float4* __restrict__ o = (float4*)(out + (size_t)mat * 4096);
    #pragma unroll
    for (int r = 0; r < 8; ++r) {
        float ur = uu[r];
        float4 lo, hi;
        lo.x = b[r][0] * ur * vv[0]; lo.y = b[r][1] * ur * vv[1];
        lo.z = b[r][2] * ur * vv[2]; lo.w = b[r][3] * ur * vv[3];
        hi.x = b[r][4] * ur * vv[4]; hi.y = b[r][5] * ur * vv[5];
        hi.z = b[r][6] * ur * vv[6]; hi.w = b[r][7] * ur * vv[7];
        o[(8 * bi + r) * 16 + 2 * bj + 0] = lo;
        o[(8 * bi + r) * 16 + 2 * bj + 1] = hi;
    }
}

extern "C" void kernel_launch(void* const* d_in, const int* in_sizes, int n_in,
                              void* d_out, int out_size, void* d_ws, size_t ws_size,
                              hipStream_t stream) {
    const float* x = (const float*)d_in[0];
    float* out = (float*)d_out;
    const int nmat = in_sizes[0] / 4096;          // 8192 matrices of 64x64
    const int blocks = (nmat + 3) / 4;            // 4 matrices (waves) per block
    sinkhorn_kernel<<<blocks, 256, 0, stream>>>(x, out, nmat);
}

// Round 2
// 249.619 us; speedup vs baseline: 1.0516x; 1.0516x over previous
//
#include <hip/hip_runtime.h>

#define ITERS 20
#define EPS 1e-9f

// One wave (64 lanes) per 64x64 matrix. Lane (bi,bj) owns the 8x8 sub-block
// rows [8bi,8bi+8), cols [8bj,8bj+8), plus replicated scale vectors
// uu[r]=u[8bi+r], vv[c]=v[8bj+c]. Sinkhorn iterate is M = E .* (u v^T),
// so only u,v are updated; matrix E=exp(x) stays in registers.
//
// Cross-lane reduces use DPP (VALU pipe, ~2cy) for strides 1,2,4(->xor7),8;
// only strides 16,32 touch the DS pipe (ds_swizzle/bpermute).

template <int CTRL>
__device__ __forceinline__ float dpp_add(float x) {
    int yi = __builtin_amdgcn_update_dpp(0, __float_as_int(x), CTRL, 0xf, 0xf, true);
    return x + __int_as_float(yi);
}

__global__ __launch_bounds__(256, 4) void sinkhorn_kernel(
        const float* __restrict__ x, float* __restrict__ out, int nmat) {
    const int lane = threadIdx.x & 63;
    const int wave = threadIdx.x >> 6;
    const int mat  = blockIdx.x * 4 + wave;
    if (mat >= nmat) return;
    const int bi = lane >> 3;   // block-row 0..7
    const int bj = lane & 7;    // block-col 0..7

    const float4* __restrict__ xin = (const float4*)(x + (size_t)mat * 4096);

    // Load 8x8 block as 2 float4 per row, apply exp.
    float b[8][8];
    #pragma unroll
    for (int r = 0; r < 8; ++r) {
        float4 lo = xin[(8 * bi + r) * 16 + 2 * bj + 0];
        float4 hi = xin[(8 * bi + r) * 16 + 2 * bj + 1];
        b[r][0] = __expf(lo.x); b[r][1] = __expf(lo.y);
        b[r][2] = __expf(lo.z); b[r][3] = __expf(lo.w);
        b[r][4] = __expf(hi.x); b[r][5] = __expf(hi.y);
        b[r][6] = __expf(hi.z); b[r][7] = __expf(hi.w);
    }

    float uu[8], vv[8];
    #pragma unroll
    for (int i = 0; i < 8; ++i) { uu[i] = 1.0f; vv[i] = 1.0f; }

    for (int it = 0; it < ITERS; ++it) {
        // ---- row normalization: rowsum_i = u_i * sum_j E[i,j] v_j ----
        float p[8];
        #pragma unroll
        for (int r = 0; r < 8; ++r) {
            float s = 0.0f;
            #pragma unroll
            for (int c = 0; c < 8; ++c) s = fmaf(b[r][c], vv[c], s);
            p[r] = s;
        }
        // all-reduce across the 8 lanes sharing bi (lane bits 0-2) — pure DPP
        #pragma unroll
        for (int r = 0; r < 8; ++r) p[r] = dpp_add<0xB1>(p[r]);   // quad_perm xor1
        #pragma unroll
        for (int r = 0; r < 8; ++r) p[r] = dpp_add<0x4E>(p[r]);   // quad_perm xor2
        #pragma unroll
        for (int r = 0; r < 8; ++r) p[r] = dpp_add<0x141>(p[r]);  // row_half_mirror = xor7
        #pragma unroll
        for (int r = 0; r < 8; ++r) {
            float S = fmaf(uu[r], p[r], EPS);      // rowsum + eps
            uu[r] *= __builtin_amdgcn_rcpf(S);
        }

        // ---- col normalization: colsum_j = v_j * sum_i E[i,j] u_i ----
        float q[8];
        #pragma unroll
        for (int c = 0; c < 8; ++c) {
            float s = 0.0f;
            #pragma unroll
            for (int r = 0; r < 8; ++r) s = fmaf(b[r][c], uu[r], s);
            q[c] = s;
        }
        // all-reduce across the 8 lanes sharing bj (lane bits 3-5)
        #pragma unroll
        for (int c = 0; c < 8; ++c) q[c] = dpp_add<0x128>(q[c]);  // row_ror:8 = xor8
        #pragma unroll
        for (int c = 0; c < 8; ++c) q[c] += __shfl_xor(q[c], 16, 64);
        #pragma unroll
        for (int c = 0; c < 8; ++c) q[c] += __shfl_xor(q[c], 32, 64);
        #pragma unroll
        for (int c = 0; c < 8; ++c) {
            float T = fmaf(vv[c], q[c], EPS);      // colsum + eps
            vv[c] *= __builtin_amdgcn_rcpf(T);
        }
    }

    // ---- epilogue: out = E .* (u v^T) ----
    float4* __restrict__ o = (float4*)(out + (size_t)mat * 4096);
    #pragma unroll
    for (int r = 0; r < 8; ++r) {
        float ur = uu[r];
        float4 lo, hi;
        lo.x = b[r][0] * ur * vv[0]; lo.y = b[r][1] * ur * vv[1];
        lo.z = b[r][2] * ur * vv[2]; lo.w = b[r][3] * ur * vv[3];
        hi.x = b[r][4] * ur * vv[4]; hi.y = b[r][5] * ur * vv[5];
        hi.z = b[r][6] * ur * vv[6]; hi.w = b[r][7] * ur * vv[7];
        o[(8 * bi + r) * 16 + 2 * bj + 0] = lo;
        o[(8 * bi + r) * 16 + 2 * bj + 1] = hi;
    }
}

extern "C" void kernel_launch(void* const* d_in, const int* in_sizes, int n_in,
                              void* d_out, int out_size, void* d_ws, size_t ws_size,
                              hipStream_t stream) {
    const float* x = (const float*)d_in[0];
    float* out = (float*)d_out;
    const int nmat = in_sizes[0] / 4096;          // 8192 matrices of 64x64
    const int blocks = (nmat + 3) / 4;            // 4 matrices (waves) per block
    sinkhorn_kernel<<<blocks, 256, 0, stream>>>(x, out, nmat);
}